// Round 2
// baseline (233.102 us; speedup 1.0000x reference)
//
#include <hip/hip_runtime.h>
#include <math.h>

#define NXC 200   // grid edge
#define NBB 512   // batch
#define TPB 512   // threads per block (8 waves)
#define WPB 8     // waves per block
#define ITER 25   // rows per wave: i = wave + 8*k, k=0..24 (uniform, no guards)

// One block per batch. Wave w owns rows i = w + 8k (exactly 25 each).
// Lane l<50 loads float4 covering columns 4l..4l+3.
// Depth-4 software pipeline: 8 float4 loads in flight per wave at all times
// (statically indexed buffers -> registers, not scratch).
// Row sums: 3 shuffle-adds in-loop (lanes 0..7 hold stride-8 comb partials,
// stored to LDS), finished after the loop. Column sums accumulate per-lane
// in registers. Boundary rows/cols re-read from global post-loop (L2-hot)
// instead of predicated in-loop captures. No workspace, no extra HBM traffic.
__global__ __launch_bounds__(TPB, 4) void heat_loss_kernel(
    const float* __restrict__ layout, const float* __restrict__ heat,
    float* __restrict__ out) {
  const int b    = blockIdx.x;
  const int tid  = threadIdx.x;
  const int wave = tid >> 6;
  const int lane = tid & 63;
  const bool act = (lane < 50);

  const float4* __restrict__ hp =
      reinterpret_cast<const float4*>(heat + (size_t)b * NXC * NXC);
  const float4* __restrict__ lp =
      reinterpret_cast<const float4*>(layout + (size_t)b * NXC * NXC);

  __shared__ float s_hc[WPB][NXC];  // per-wave column partials (heat)
  __shared__ float s_lc[WPB][NXC];  // (layout)
  __shared__ float s_ph[NXC][8];    // 8 row-sum partials per row (heat)
  __shared__ float s_pl[NXC][8];    // (layout)
  __shared__ float s_CS[NXC];       // total column sums (heat)
  __shared__ float s_CL[NXC];       // (layout)
  __shared__ float s_RS[NXC];       // row sums (heat)
  __shared__ float s_RL[NXC];       // row sums (layout)
  __shared__ float s_red[4][WPB];   // minv/maxv/minh/maxh per wave
  __shared__ float s_sum[WPB];      // contrib partial per wave

  float hc0=0.f,hc1=0.f,hc2=0.f,hc3=0.f;
  float lc0=0.f,lc1=0.f,lc2=0.f,lc3=0.f;

  float4 hb4[4], lb4[4];
  #pragma unroll
  for (int s = 0; s < 4; ++s) {
    hb4[s] = make_float4(0.f,0.f,0.f,0.f);
    lb4[s] = make_float4(0.f,0.f,0.f,0.f);
    if (act) {
      const int i = wave + 8 * s;
      hb4[s] = hp[i * 50 + lane];
      lb4[s] = lp[i * 50 + lane];
    }
  }

  #pragma unroll
  for (int k = 0; k < ITER; ++k) {
    const int s = k & 3;
    const float4 hv = hb4[s];
    const float4 lv = lb4[s];
    if (k + 4 < ITER && act) {
      const int ip = wave + 8 * (k + 4);
      hb4[s] = hp[ip * 50 + lane];
      lb4[s] = lp[ip * 50 + lane];
    }

    hc0 += hv.x; hc1 += hv.y; hc2 += hv.z; hc3 += hv.w;
    lc0 += lv.x; lc1 += lv.y; lc2 += lv.z; lc3 += lv.w;

    // 3-deep partial reduce: lanes 0..7 end with stride-8 comb partials
    // whose sum over p=0..7 is the full row sum (inactive lanes carry 0).
    float hs = (hv.x + hv.y) + (hv.z + hv.w);
    float ls = (lv.x + lv.y) + (lv.z + lv.w);
    hs += __shfl_down(hs, 32); ls += __shfl_down(ls, 32);
    hs += __shfl_down(hs, 16); ls += __shfl_down(ls, 16);
    hs += __shfl_down(hs, 8);  ls += __shfl_down(ls, 8);
    if (lane < 8) {
      const int i = wave + 8 * k;
      s_ph[i][lane] = hs;
      s_pl[i][lane] = ls;
    }
  }

  if (act) {
    s_hc[wave][4*lane+0] = hc0; s_hc[wave][4*lane+1] = hc1;
    s_hc[wave][4*lane+2] = hc2; s_hc[wave][4*lane+3] = hc3;
    s_lc[wave][4*lane+0] = lc0; s_lc[wave][4*lane+1] = lc1;
    s_lc[wave][4*lane+2] = lc2; s_lc[wave][4*lane+3] = lc3;
  }
  __syncthreads();

  if (tid < NXC) {
    float a = 0.f, c = 0.f, rh = 0.f, rl = 0.f;
    #pragma unroll
    for (int w = 0; w < WPB; ++w) { a += s_hc[w][tid]; c += s_lc[w][tid]; }
    #pragma unroll
    for (int p = 0; p < 8; ++p)   { rh += s_ph[tid][p]; rl += s_pl[tid][p]; }
    s_CS[tid] = a; s_CL[tid] = c; s_RS[tid] = rh; s_RL[tid] = rl;
  }
  __syncthreads();

  const float* __restrict__ hb = heat + (size_t)b * NXC * NXC;
  const float COF = (float)(0.25 * (0.1/199.0) * (0.1/199.0));
  float dv = 0.f, dh = 0.f;
  if (tid < NXC) {
    const int j  = tid;
    const int jm = (j == 0) ? 1 : j - 1;
    const int jp = (j == NXC-1) ? NXC-2 : j + 1;

    // boundary rows 0,1,198,199 (coalesced, L2/LLC-hot re-reads)
    const float h0   = hb[0*NXC + j];
    const float h1   = hb[1*NXC + j];
    const float h198 = hb[198*NXC + j];
    const float h199 = hb[199*NXC + j];
    float Sv = 0.25f * (2.f*s_CS[j]
                        + h1 - h199        // +h[1,j]   - h[199,j]
                        + h198 - h0        // +h[198,j] - h[0,j]
                        + s_CS[jm] + s_CS[jp])
             + COF * s_CL[j];
    dv = fabsf(Sv - s_CS[j]) * (1.f / NXC);

    // boundary cols 0,1,198,199 of row j via two aligned float4 loads
    const float4 c03 = *reinterpret_cast<const float4*>(hb + (size_t)j*NXC);
    const float4 c69 = *reinterpret_cast<const float4*>(hb + (size_t)j*NXC + 196);
    float Sh = 0.25f * (2.f*s_RS[j]
                        + c03.y - c69.w    // +h[j,1]   - h[j,199]
                        + c69.z - c03.x    // +h[j,198] - h[j,0]
                        + s_RS[jm] + s_RS[jp])
             + COF * s_RL[j];
    dh = fabsf(Sh - s_RS[j]) * (1.f / NXC);
  }

  // per-batch min/max of dv and dh (dv,dh >= 0 so max pad 0 is safe)
  float mnv = (tid < NXC) ? dv : INFINITY;
  float mxv = dv;
  float mnh = (tid < NXC) ? dh : INFINITY;
  float mxh = dh;
  #pragma unroll
  for (int off = 32; off > 0; off >>= 1) {
    mnv = fminf(mnv, __shfl_down(mnv, off));
    mxv = fmaxf(mxv, __shfl_down(mxv, off));
    mnh = fminf(mnh, __shfl_down(mnh, off));
    mxh = fmaxf(mxh, __shfl_down(mxh, off));
  }
  if (lane == 0) {
    s_red[0][wave] = mnv;
    s_red[1][wave] = mxv;
    s_red[2][wave] = mnh;
    s_red[3][wave] = mxh;
  }
  __syncthreads();

  float MNV = INFINITY, MXV = -INFINITY, MNH = INFINITY, MXH = -INFINITY;
  #pragma unroll
  for (int w = 0; w < WPB; ++w) {
    MNV = fminf(MNV, s_red[0][w]); MXV = fmaxf(MXV, s_red[1][w]);
    MNH = fminf(MNH, s_red[2][w]); MXH = fmaxf(MXH, s_red[3][w]);
  }

  float contrib = 0.f;
  if (tid < NXC) {
    contrib = 10.f * (dv - MNV) * dv / (MXV - MNV)
            + 10.f * (dh - MNH) * dh / (MXH - MNH);
  }
  #pragma unroll
  for (int off = 32; off > 0; off >>= 1) contrib += __shfl_down(contrib, off);
  if (lane == 0) s_sum[wave] = contrib;
  __syncthreads();
  if (tid == 0) {
    float tot = 0.f;
    #pragma unroll
    for (int w = 0; w < WPB; ++w) tot += s_sum[w];
    atomicAdd(out, tot * (1.f / ((float)NBB * (float)NXC)));
  }
}

extern "C" void kernel_launch(void* const* d_in, const int* in_sizes, int n_in,
                              void* d_out, int out_size, void* d_ws, size_t ws_size,
                              hipStream_t stream) {
  const float* layout = (const float*)d_in[0];
  const float* heat   = (const float*)d_in[1];
  float* out = (float*)d_out;

  // d_out is poisoned to 0xAA before every timed launch — zero it first.
  hipMemsetAsync(out, 0, (size_t)out_size * sizeof(float), stream);
  heat_loss_kernel<<<NBB, TPB, 0, stream>>>(layout, heat, out);
}